// Round 6
// baseline (229.476 us; speedup 1.0000x reference)
//
#include <hip/hip_runtime.h>
#include <cmath>

typedef __attribute__((ext_vector_type(8))) short short8;
typedef __attribute__((ext_vector_type(4))) float floatx4;

#define T_TOK 32768
#define DIMK 512
#define AKT 2097152  // 32768*64 shorts: A-operand K-tile stride (M=32768 both GEMMs)

__device__ __forceinline__ unsigned short f2bf(float f) {
  union { float f; unsigned int u; } v; v.f = f;
  unsigned int r = (v.u + 0x7fffu + ((v.u >> 16) & 1u)) >> 16;
  return (unsigned short)r;
}
__device__ __forceinline__ float bf2f(unsigned short h) {
  union { unsigned int u; float f; } v; v.u = ((unsigned int)h) << 16;
  return v.f;
}

// async global->LDS 16B per lane: HW writes lane i at ldsbase + i*16
__device__ __forceinline__ void gload_lds16(const unsigned short* g, unsigned short* ldsbase) {
  __builtin_amdgcn_global_load_lds(
      (const __attribute__((address_space(1))) unsigned int*)g,
      (__attribute__((address_space(3))) unsigned int*)ldsbase, 16, 0, 0);
}

// ------- prep: [blocks 0..2047] weights->bf16 (K-TILED) + rope + zero; [2048..10239] rmsnorm -------
// All GEMM operands stored K-tiled: X_t[kt][row][64] -> staging slabs contiguous.
// Wb logical rows: 0..511 = wq; rows 512..1023 interleaved per KV head:
//   row 512+h*128+d <- wk[h*64+d], row 512+h*128+64+d <- wv[h*64+d].
__global__ __launch_bounds__(256) void k_prep(const float* __restrict__ x,
    const float* __restrict__ norm_w, const float* __restrict__ wq,
    const float* __restrict__ wk, const float* __restrict__ wv,
    const float* __restrict__ wo, unsigned short* __restrict__ Wb,
    unsigned short* __restrict__ wob, float2* __restrict__ rope,
    float* __restrict__ KVz, unsigned short* __restrict__ xn) {
  if (blockIdx.x < 2048) {
    int i = blockIdx.x * 256 + threadIdx.x;  // 524288
    int R = i >> 9, col = i & 511;
    float v;
    if (i < 262144) {
      v = wq[i];
    } else {
      int h = (R - 512) >> 7, rem = (R - 512) & 127;
      if (rem < 64) v = wk[(h * 64 + rem) * 512 + col];
      else          v = wv[(h * 64 + rem - 64) * 512 + col];
    }
    Wb[(col >> 6) * 65536 + R * 64 + (col & 63)] = f2bf(v);
    if (i < 262144) {
      wob[(col >> 6) * 32768 + R * 64 + (col & 63)] = f2bf(wo[i]);
      int s = i >> 5, m = i & 31;
      const double c0 = 0.74989420933245582;   // 10^(-1/8)
      double c1 = c0 * c0, c2 = c1 * c1, c3 = c2 * c2, c4 = c3 * c3;
      double p = 1.0;
      if (m & 1)  p *= c0;
      if (m & 2)  p *= c1;
      if (m & 4)  p *= c2;
      if (m & 8)  p *= c3;
      if (m & 16) p *= c4;
      double ang = (double)s * p;
      const double TWO_PI = 6.2831853071795864769;
      double q = rint(ang * (1.0 / TWO_PI));
      double r = fma(-q, TWO_PI, ang);
      float rf = (float)r;
      rope[i] = make_float2(cosf(rf), sinf(rf));
    }
    if (i < 2048) KVz[i] = 0.f;   // zero KV (1024 f32) + Ksum (1024 f32)
  } else {
    int bid = blockIdx.x - 2048;
    int wave = threadIdx.x >> 6, lane = threadIdx.x & 63;
    size_t t = (size_t)bid * 4 + wave;
    const float4* xr = (const float4*)(x + t * DIMK);
    float4 a = xr[lane * 2];
    float4 b = xr[lane * 2 + 1];
    float ss = a.x * a.x + a.y * a.y + a.z * a.z + a.w * a.w
             + b.x * b.x + b.y * b.y + b.z * b.z + b.w * b.w;
    #pragma unroll
    for (int off = 32; off >= 1; off >>= 1) ss += __shfl_xor(ss, off, 64);
    float scale = rsqrtf(ss * (1.0f / DIMK) + 1e-6f);
    const float4* wr = (const float4*)norm_w;
    float4 w0 = wr[lane * 2], w1 = wr[lane * 2 + 1];
    uint4 o;
    o.x = (unsigned int)f2bf(a.x * scale * w0.x) | ((unsigned int)f2bf(a.y * scale * w0.y) << 16);
    o.y = (unsigned int)f2bf(a.z * scale * w0.z) | ((unsigned int)f2bf(a.w * scale * w0.w) << 16);
    o.z = (unsigned int)f2bf(b.x * scale * w1.x) | ((unsigned int)f2bf(b.y * scale * w1.y) << 16);
    o.w = (unsigned int)f2bf(b.z * scale * w1.z) | ((unsigned int)f2bf(b.w * scale * w1.w) << 16);
    *(uint4*)(xn + (size_t)(lane >> 3) * AKT + t * 64 + (lane & 7) * 8) = o;
  }
}

// ------- GEMM: C(M,N) = A(M,512) * Bw(N,512)^T, operands K-TILED -------
// 128x128 tile, BK=64, 4 waves, single-buffered 2-phase loop (r0-verified inner
// loop), 32KB static LDS -> multi-block/CU for TLP overlap. K-tiled staging:
// each gload_lds16 is a contiguous 1KB burst. XCD remap (r4-verified): XCD x
// owns m-tiles [32x,32x+32), n fastest -> A L2-hot across 8 (or 4) blocks.
// FUSE (GEMM1 n0>=512): n-tile = one KV head (K cols 0-63 | V cols 64-127);
// epilogue computes rope+phi on K, multiplies by V staged in LDS (Vs overlays
// As+Bs, 32KB, group-rotated 2-way bank access), atomically accumulates
// KV/Ksum; no C-write. Replaces k_kvred.
template <bool BF16_OUT, bool FUSE>
__global__ __launch_bounds__(256) void k_gemm128(const unsigned short* __restrict__ A,
    const unsigned short* __restrict__ Bw, void* __restrict__ Cv, int ldc, int nrows, int lgn,
    const float2* __restrict__ rope, float* __restrict__ KV, float* __restrict__ Ksum) {
  __shared__ __align__(16) unsigned short smem[16384];   // As[8192] | Bs[8192] = 32KB
  unsigned short* const As = smem;
  unsigned short* const Bs = smem + 8192;

  const int tid = threadIdx.x;
  const int wave = tid >> 6, lane = tid & 63;
  const int r = lane & 15, quad = lane >> 4, r7 = r & 7;
  const int wm = (wave >> 1) * 64, wn = (wave & 1) * 64;

  // XCD remap: xcd = bid&7 owns 32 consecutive m-tiles; n fastest within XCD.
  const int ngy = gridDim.y;
  const int bid = blockIdx.x + gridDim.x * blockIdx.y;
  const int xcd = bid & 7;
  const int j = bid >> 3;
  const int mt = xcd * 32 + (j >> lgn);
  const int nt = j & (ngy - 1);
  const int m0 = mt * 128, n0 = nt * 128;

  // staging: lane covers row (lane>>3), col-block (lane&7)^(row&7) within 1KB slab
  const int srow = lane >> 3;
  const int scb = (lane & 7) ^ srow;
  const size_t bkt = (size_t)nrows * 64;           // B K-tile stride (shorts)
  const unsigned short* const Ag = A  + (size_t)(m0 + wave * 32 + srow) * 64 + scb * 8;
  const unsigned short* const Bg = Bw + (size_t)(n0 + wave * 32 + srow) * 64 + scb * 8;
  unsigned short* const Al = As + wave * 32 * 64;
  unsigned short* const Bl = Bs + wave * 32 * 64;

  floatx4 acc[4][4];
  #pragma unroll
  for (int i = 0; i < 4; i++)
    #pragma unroll
    for (int jj = 0; jj < 4; jj++)
      acc[i][jj] = (floatx4){0.f, 0.f, 0.f, 0.f};

  for (int kt = 0; kt < 8; kt++) {
    #pragma unroll
    for (int li = 0; li < 4; li++) {
      gload_lds16(Ag + (size_t)kt * AKT + li * 512, Al + li * 512);
      gload_lds16(Bg + (size_t)kt * bkt + li * 512, Bl + li * 512);
    }
    __syncthreads();
    #pragma unroll
    for (int kk = 0; kk < 64; kk += 32) {
      const int sw = ((((kk >> 3) + quad)) ^ r7) * 8;  // swizzled col offset (shorts)
      short8 af[4], bfv[4];
      #pragma unroll
      for (int i = 0; i < 4; i++)
        af[i] = *(const short8*)&As[(wm + i * 16 + r) * 64 + sw];
      #pragma unroll
      for (int jj = 0; jj < 4; jj++)
        bfv[jj] = *(const short8*)&Bs[(wn + jj * 16 + r) * 64 + sw];
      #pragma unroll
      for (int i = 0; i < 4; i++)
        #pragma unroll
        for (int jj = 0; jj < 4; jj++)
          acc[i][jj] = __builtin_amdgcn_mfma_f32_16x16x32_bf16(af[i], bfv[jj], acc[i][jj], 0, 0, 0);
    }
    __syncthreads();
  }

  if (FUSE && n0 >= 512) {
    // acc cols: wn=0 waves hold K dims 0-63, wn=64 waves hold V dims 0-63 of
    // head kh. Vs[t][d] (128x64 f32, 32KB) overlays As|Bs; group-rotation
    // ((d>>4)+(t>>2))&3 -> every access 2-way banked (free, m136).
#define VSW(t, d) ((t) * 64 + ((d) & 15) + (((((d) >> 4) + ((t) >> 2)) & 3) << 4))
    const int b = m0 >> 13;
    const int kh = (n0 - 512) >> 7;
    float* const Vs = (float*)smem;
    if (wn) {                                  // V-wave: dump acc to LDS
      #pragma unroll
      for (int i = 0; i < 4; i++)
        #pragma unroll
        for (int j2 = 0; j2 < 4; j2++)
          #pragma unroll
          for (int p = 0; p < 4; p++) {
            int t = wm + i * 16 + quad * 4 + p;
            Vs[VSW(t, j2 * 16 + r)] = acc[i][j2][p];
          }
    }
    __syncthreads();
    if (!wn) {                                 // K-wave: rope+phi, mul V, reduce
      float kvp[4] = {0.f, 0.f, 0.f, 0.f};
      float ksp[4] = {0.f, 0.f, 0.f, 0.f};
      #pragma unroll
      for (int i = 0; i < 4; i++)
        #pragma unroll
        for (int p = 0; p < 4; p++) {
          int t = wm + i * 16 + quad * 4 + p;
          int pos = (m0 + t) & 8191;
          #pragma unroll
          for (int j2 = 0; j2 < 4; j2++) {
            float v = acc[i][j2][p];
            float vp = __shfl_xor(v, 1, 64);
            int d = j2 * 16 + r;
            float2 cs = rope[pos * 32 + (d >> 1)];
            float rk = (r & 1) ? (vp * cs.y + v * cs.x) : (v * cs.x - vp * cs.y);
            rk = rk > 0.f ? rk + 1.f : __expf(rk);
            kvp[j2] += rk * Vs[VSW(t, d)];
            ksp[j2] += rk;
          }
        }
      #pragma unroll
      for (int j2 = 0; j2 < 4; j2++) {
        kvp[j2] += __shfl_xor(kvp[j2], 16, 64); kvp[j2] += __shfl_xor(kvp[j2], 32, 64);
        ksp[j2] += __shfl_xor(ksp[j2], 16, 64); ksp[j2] += __shfl_xor(ksp[j2], 32, 64);
      }
      if (lane < 16) {
        int base = (b * 4 + kh) * 64 + r;
        #pragma unroll
        for (int j2 = 0; j2 < 4; j2++) {
          atomicAdd(&KV[base + j2 * 16], kvp[j2]);
          atomicAdd(&Ksum[base + j2 * 16], ksp[j2]);
        }
      }
    }
#undef VSW
  } else {
    // C write (row-major). C/D layout: col = lane&15, row = quad*4 + p
    #pragma unroll
    for (int i = 0; i < 4; i++)
      #pragma unroll
      for (int j2 = 0; j2 < 4; j2++) {
        int row = m0 + wm + i * 16 + quad * 4;
        int col = n0 + wn + j2 * 16 + r;
        #pragma unroll
        for (int p = 0; p < 4; p++) {
          if constexpr (BF16_OUT) {
            ((unsigned short*)Cv)[(size_t)(row + p) * ldc + col] = f2bf(acc[i][j2][p]);
          } else {
            ((float*)Cv)[(size_t)(row + p) * ldc + col] = acc[i][j2][p];
          }
        }
      }
  }
}

// ------- Q path: half-wave (32 lanes) per head, one uint pair per lane -------
// Reads qkv row-major (GEMM1's Q C-write); writes Yb K-TILED for GEMM2 staging.
__global__ __launch_bounds__(256) void k_qkern(const unsigned short* __restrict__ qkv,
    const float2* __restrict__ rope, const float* __restrict__ KV,
    const float* __restrict__ Ksum, unsigned short* __restrict__ Yb) {
  const int h = threadIdx.x >> 5;   // head 0..7
  const int pr = threadIdx.x & 31;  // rotation pair 0..31
  for (int t = blockIdx.x; t < T_TOK; t += gridDim.x) {
    int b = t >> 13, pos = t & 8191;
    unsigned int qp = *(const unsigned int*)(qkv + (size_t)t * 512 + h * 64 + 2 * pr);
    float qx = bf2f((unsigned short)(qp & 0xffffu));
    float qy = bf2f((unsigned short)(qp >> 16));
    float2 cs = rope[pos * 32 + pr];
    float ar = qx * cs.x - qy * cs.y;
    float ai = qx * cs.y + qy * cs.x;
    ar = ar > 0.f ? ar + 1.f : __expf(ar);
    ai = ai > 0.f ? ai + 1.f : __expf(ai);
    int bk = b * 4 + (h >> 1);
    float2 ks = *(const float2*)(Ksum + bk * 64 + 2 * pr);
    float z = ar * ks.x + ai * ks.y;
    #pragma unroll
    for (int off = 16; off >= 1; off >>= 1) z += __shfl_xor(z, off, 64);  // stays in half-wave
    float2 kv = *(const float2*)(KV + bk * 64 + 2 * pr);
    float inv = 1.0f / (z + 1e-6f);
    unsigned int o = (unsigned int)f2bf(ar * kv.x * inv)
                   | ((unsigned int)f2bf(ai * kv.y * inv) << 16);
    // K-tiled: head h's 64 dims are exactly K-tile h -> Yb_t[h][t][2*pr]
    *(unsigned int*)(Yb + (size_t)h * AKT + t * 64 + 2 * pr) = o;
  }
}

extern "C" void kernel_launch(void* const* d_in, const int* in_sizes, int n_in,
                              void* d_out, int out_size, void* d_ws, size_t ws_size,
                              hipStream_t stream) {
  const float* x = (const float*)d_in[0];
  const float* norm_w = (const float*)d_in[1];
  const float* wq = (const float*)d_in[2];
  const float* wk = (const float*)d_in[3];
  const float* wv = (const float*)d_in[4];
  const float* wo = (const float*)d_in[5];
  float* out = (float*)d_out;

  char* ws = (char*)d_ws;
  unsigned short* xn  = (unsigned short*)(ws);                  // 33,554,432 B (K-tiled)
  unsigned short* Wb  = (unsigned short*)(ws + 33554432);       //  1,048,576 B (K-tiled)
  unsigned short* wob = (unsigned short*)(ws + 34603008);       //    524,288 B (K-tiled)
  unsigned short* qkv = (unsigned short*)(ws + 35127296);       // 33,554,432 B (Q only, row-major)
  float2* rope        = (float2*)(ws + 102236160);              //  2,097,152 B
  float* KV           = (float*)(ws + 104333312);               //      4,096 B
  float* Ksum         = (float*)(ws + 104337408);               //      4,096 B
  unsigned short* Yb  = (unsigned short*)(ws + 104341504);      // 33,554,432 B (K-tiled)

  k_prep<<<10240, 256, 0, stream>>>(x, norm_w, wq, wk, wv, wo, Wb, wob, rope, KV, xn);
  k_gemm128<true, true><<<dim3(256, 8), 256, 0, stream>>>(
      xn, Wb, (void*)qkv, 512, 1024, 3, rope, KV, Ksum);
  k_qkern<<<4096, 256, 0, stream>>>(qkv, rope, KV, Ksum, Yb);
  k_gemm128<false, false><<<dim3(256, 4), 256, 0, stream>>>(
      Yb, wob, (void*)out, 512, 512, 2, nullptr, nullptr, nullptr);
}

// Round 7
// 221.997 us; speedup vs baseline: 1.0337x; 1.0337x over previous
//
#include <hip/hip_runtime.h>
#include <cmath>

typedef __attribute__((ext_vector_type(8))) short short8;
typedef __attribute__((ext_vector_type(4))) float floatx4;

#define T_TOK 32768
#define DIMK 512

__device__ __forceinline__ unsigned short f2bf(float f) {
  union { float f; unsigned int u; } v; v.f = f;
  unsigned int r = (v.u + 0x7fffu + ((v.u >> 16) & 1u)) >> 16;
  return (unsigned short)r;
}
__device__ __forceinline__ float bf2f(unsigned short h) {
  union { unsigned int u; float f; } v; v.u = ((unsigned int)h) << 16;
  return v.f;
}

// async global->LDS 16B per lane: HW writes lane i at ldsbase + i*16
__device__ __forceinline__ void gload_lds16(const unsigned short* g, unsigned short* ldsbase) {
  __builtin_amdgcn_global_load_lds(
      (const __attribute__((address_space(1))) unsigned int*)g,
      (__attribute__((address_space(3))) unsigned int*)ldsbase, 16, 0, 0);
}

// ------- prep: [blocks 0..2047] weights->bf16 + rope + zero; [2048..10239] rmsnorm -------
// Row-major operand layout (r2/r4-verified; K-tiled regressed -- latency/MLP regime).
// Wb rows 0..511 = wq; rows 512..1023 interleaved per KV head:
//   row 512+h*128+d <- wk[h*64+d], row 512+h*128+64+d <- wv[h*64+d]
// so a 256-wide n-tile at n0 in {512,768} holds matched K,V for 2 heads.
__global__ __launch_bounds__(256) void k_prep(const float* __restrict__ x,
    const float* __restrict__ norm_w, const float* __restrict__ wq,
    const float* __restrict__ wk, const float* __restrict__ wv,
    const float* __restrict__ wo, unsigned short* __restrict__ Wb,
    unsigned short* __restrict__ wob, float2* __restrict__ rope,
    float* __restrict__ KVz, unsigned short* __restrict__ xn) {
  if (blockIdx.x < 2048) {
    int i = blockIdx.x * 256 + threadIdx.x;  // 524288
    float v;
    if (i < 262144) {
      v = wq[i];
    } else {
      int R = i >> 9, col = i & 511;
      int h = (R - 512) >> 7, rem = (R - 512) & 127;
      if (rem < 64) v = wk[(h * 64 + rem) * 512 + col];
      else          v = wv[(h * 64 + rem - 64) * 512 + col];
    }
    Wb[i] = f2bf(v);
    if (i < 262144) {
      wob[i] = f2bf(wo[i]);
      int s = i >> 5, m = i & 31;
      const double c0 = 0.74989420933245582;   // 10^(-1/8)
      double c1 = c0 * c0, c2 = c1 * c1, c3 = c2 * c2, c4 = c3 * c3;
      double p = 1.0;
      if (m & 1)  p *= c0;
      if (m & 2)  p *= c1;
      if (m & 4)  p *= c2;
      if (m & 8)  p *= c3;
      if (m & 16) p *= c4;
      double ang = (double)s * p;
      const double TWO_PI = 6.2831853071795864769;
      double q = rint(ang * (1.0 / TWO_PI));
      double r = fma(-q, TWO_PI, ang);
      float rf = (float)r;
      rope[i] = make_float2(cosf(rf), sinf(rf));
    }
    if (i < 2048) KVz[i] = 0.f;   // zero KV (1024 f32) + Ksum (1024 f32)
  } else {
    int bid = blockIdx.x - 2048;
    int wave = threadIdx.x >> 6, lane = threadIdx.x & 63;
    size_t t = (size_t)bid * 4 + wave;
    const float4* xr = (const float4*)(x + t * DIMK);
    float4 a = xr[lane * 2];
    float4 b = xr[lane * 2 + 1];
    float ss = a.x * a.x + a.y * a.y + a.z * a.z + a.w * a.w
             + b.x * b.x + b.y * b.y + b.z * b.z + b.w * b.w;
    #pragma unroll
    for (int off = 32; off >= 1; off >>= 1) ss += __shfl_xor(ss, off, 64);
    float scale = rsqrtf(ss * (1.0f / DIMK) + 1e-6f);
    const float4* wr = (const float4*)norm_w;
    float4 w0 = wr[lane * 2], w1 = wr[lane * 2 + 1];
    uint4 o;
    o.x = (unsigned int)f2bf(a.x * scale * w0.x) | ((unsigned int)f2bf(a.y * scale * w0.y) << 16);
    o.y = (unsigned int)f2bf(a.z * scale * w0.z) | ((unsigned int)f2bf(a.w * scale * w0.w) << 16);
    o.z = (unsigned int)f2bf(b.x * scale * w1.x) | ((unsigned int)f2bf(b.y * scale * w1.y) << 16);
    o.w = (unsigned int)f2bf(b.z * scale * w1.z) | ((unsigned int)f2bf(b.w * scale * w1.w) << 16);
    *(uint4*)(xn + t * DIMK + lane * 8) = o;
  }
}

// ------- GEMM: C(M,N) = A(M,512) * Bw(N,512)^T, row-major operands -------
// 256x256 tile, BK=64, 8 waves, 8-phase counted-vmcnt schedule + setprio
// (r2-verified; best measured: 51.5/50.1us). r2's spread XCD mapping (m-fast
// within XCD chunk -- keeps memory parallelism high; m-chunked remap regressed).
// FUSE (r4-verified logic + r5's Vs bank rotation): n0>=512 tiles hold
// interleaved K|V columns; epilogue computes rope+phi on K, multiplies by V
// staged in LDS, atomically accumulates KV/Ksum; no C-write. Replaces k_kvred.
template <bool BF16_OUT, bool FUSE>
__global__ __launch_bounds__(512, 2) void k_gemm256(const unsigned short* __restrict__ A,
    const unsigned short* __restrict__ Bw, void* __restrict__ Cv, int ldc,
    const float2* __restrict__ rope, float* __restrict__ KV, float* __restrict__ Ksum) {
  constexpr int K = DIMK;
  extern __shared__ __align__(16) unsigned short smem[];
  unsigned short* const AsP = smem;            // [2][16384] shorts (64 KiB)
  unsigned short* const BsP = smem + 32768;    // [2][16384] shorts (64 KiB)

  const int tid = threadIdx.x;
  const int wave = tid >> 6, lane = tid & 63;
  const int r = lane & 15, quad = lane >> 4, r7 = r & 7;
  const int wm = (wave >> 2) * 128, wn = (wave & 3) * 64;

  // r2 spread mapping: XCD chunk of contiguous nid, m fastest within chunk.
  const int nwg = gridDim.x * gridDim.y;
  const int bid = blockIdx.x + gridDim.x * blockIdx.y;
  const int cpx = nwg >> 3;
  const int nid = (bid & 7) * cpx + (bid >> 3);
  const int m0 = (nid & 127) * 256;   // gridDim.x == 128 always here
  const int n0 = (nid >> 7) * 256;

  // staging source (pre-swizzled): lane covers row (lane>>3), col-block (lane&7)^(row&7)
  const int srow = lane >> 3;
  const int scb = (lane & 7) ^ srow;
  const unsigned short* const Asrc = A + (size_t)(m0 + wave * 8 + srow) * K + scb * 8;
  const unsigned short* const Bsrc = Bw + (size_t)(n0 + wave * 8 + srow) * K + scb * 8;
  unsigned short* const Adst = AsP + wave * 8 * 64;  // + buf*16384 + rowoff*64
  unsigned short* const Bdst = BsP + wave * 8 * 64;

#define STAGE_A(buf, h, kt) do { \
    gload_lds16(Asrc + (size_t)((h) * 128) * K + (kt) * 64, Adst + (buf) * 16384 + ((h) * 128) * 64); \
    gload_lds16(Asrc + (size_t)((h) * 128 + 64) * K + (kt) * 64, Adst + (buf) * 16384 + ((h) * 128 + 64) * 64); \
  } while (0)
#define STAGE_B(buf, h, kt) do { \
    gload_lds16(Bsrc + (size_t)((h) * 128) * K + (kt) * 64, Bdst + (buf) * 16384 + ((h) * 128) * 64); \
    gload_lds16(Bsrc + (size_t)((h) * 128 + 64) * K + (kt) * 64, Bdst + (buf) * 16384 + ((h) * 128 + 64) * 64); \
  } while (0)

  short8 af[4][2], b0[2][2], b1[2][2];
  floatx4 acc[8][4];
  #pragma unroll
  for (int i = 0; i < 8; i++)
    #pragma unroll
    for (int jj = 0; jj < 4; jj++)
      acc[i][jj] = (floatx4){0.f, 0.f, 0.f, 0.f};

#define LDA8(buf, ah) do { \
    _Pragma("unroll") for (int ii = 0; ii < 4; ii++) \
      _Pragma("unroll") for (int kk = 0; kk < 2; kk++) \
        af[ii][kk] = *(const short8*)&AsP[(buf) * 16384 + (wm + (ah) * 64 + ii * 16 + r) * 64 + ((kk * 4 + quad) ^ r7) * 8]; \
  } while (0)
#define LDB4(buf, bh, arr) do { \
    _Pragma("unroll") for (int jj = 0; jj < 2; jj++) \
      _Pragma("unroll") for (int kk = 0; kk < 2; kk++) \
        arr[jj][kk] = *(const short8*)&BsP[(buf) * 16384 + (wn + (bh) * 32 + jj * 16 + r) * 64 + ((kk * 4 + quad) ^ r7) * 8]; \
  } while (0)
#define MFMAQ(ah, bh, arr) do { \
    __builtin_amdgcn_s_setprio(1); \
    _Pragma("unroll") for (int ii = 0; ii < 4; ii++) \
      _Pragma("unroll") for (int jj = 0; jj < 2; jj++) \
        _Pragma("unroll") for (int kk = 0; kk < 2; kk++) \
          acc[(ah) * 4 + ii][(bh) * 2 + jj] = __builtin_amdgcn_mfma_f32_16x16x32_bf16( \
              af[ii][kk], arr[jj][kk], acc[(ah) * 4 + ii][(bh) * 2 + jj], 0, 0, 0); \
    __builtin_amdgcn_s_setprio(0); \
  } while (0)
#define BAR() do { asm volatile("" ::: "memory"); __builtin_amdgcn_s_barrier(); asm volatile("" ::: "memory"); } while (0)
#define VMW(n) do { asm volatile("s_waitcnt vmcnt(" #n ")" ::: "memory"); __builtin_amdgcn_sched_barrier(0); } while (0)

  // ---- prologue: kt0 -> buf0 (8 loads), kt1 -> buf1 (8 loads); wait for kt0
  STAGE_A(0, 0, 0); STAGE_B(0, 0, 0); STAGE_A(0, 1, 0); STAGE_B(0, 1, 0);
  STAGE_A(1, 0, 1); STAGE_B(1, 0, 1); STAGE_A(1, 1, 1); STAGE_B(1, 1, 1);
  VMW(8);
  BAR();

  // ---- main: iterations over K-tile pairs (kt, kt+1); kt even->buf0, odd->buf1
  #pragma unroll
  for (int it = 0; it < 3; ++it) {
    const int kt = it * 2;
    // P1: quadrant (Ah0,Bh0) of kt
    LDA8(0, 0); LDB4(0, 0, b0);
    BAR(); MFMAQ(0, 0, b0); BAR();
    // P2: (Ah0,Bh1)
    LDB4(0, 1, b1);
    BAR(); MFMAQ(0, 1, b1); BAR();
    // P3: (Ah1,Bh1); B-buf0 fully read -> stage B-buf0(kt+2)
    LDA8(0, 1); STAGE_B(0, 0, kt + 2); STAGE_B(0, 1, kt + 2);
    BAR(); MFMAQ(1, 1, b1); BAR();
    // P4: (Ah1,Bh0) regs-only; A-buf0 fully read -> stage A-buf0(kt+2)
    STAGE_A(0, 0, kt + 2); STAGE_A(0, 1, kt + 2);
    BAR(); MFMAQ(1, 0, b0); VMW(8); BAR();
    // P5: quadrant (Ah0,Bh0) of kt+1
    LDA8(1, 0); LDB4(1, 0, b0);
    BAR(); MFMAQ(0, 0, b0); BAR();
    // P6
    LDB4(1, 1, b1);
    BAR(); MFMAQ(0, 1, b1); BAR();
    // P7: B-buf1 fully read -> stage B-buf1(kt+3)
    LDA8(1, 1); STAGE_B(1, 0, kt + 3); STAGE_B(1, 1, kt + 3);
    BAR(); MFMAQ(1, 1, b1); BAR();
    // P8: A-buf1 fully read -> stage A-buf1(kt+3)
    STAGE_A(1, 0, kt + 3); STAGE_A(1, 1, kt + 3);
    BAR(); MFMAQ(1, 0, b0); VMW(8); BAR();
  }

  // ---- epilogue: kt=6 (buf0), kt=7 (buf1); nothing left to stage
  LDA8(0, 0); LDB4(0, 0, b0);
  BAR(); MFMAQ(0, 0, b0); BAR();
  LDB4(0, 1, b1);
  BAR(); MFMAQ(0, 1, b1); BAR();
  LDA8(0, 1);
  BAR(); MFMAQ(1, 1, b1); BAR();
  MFMAQ(1, 0, b0); VMW(0); BAR();
  LDA8(1, 0); LDB4(1, 0, b0);
  BAR(); MFMAQ(0, 0, b0); BAR();
  LDB4(1, 1, b1);
  BAR(); MFMAQ(0, 1, b1); BAR();
  LDA8(1, 1);
  BAR(); MFMAQ(1, 1, b1); BAR();
  MFMAQ(1, 0, b0);

  if (FUSE && n0 >= 512) {
    // ---- fused KV/Ksum epilogue (r4-verified; r5's bank rotation).
    // acc cols (wn groups): 0=K_h, 64=V_h, 128=K_{h+1}, 192=V_{h+1}.
    // Vs index group-rotated by (t>>2): 2-way bank access (free) vs 4-way.
#define VSW(t, d) ((t) * 128 + ((d) & 15) + (((((d) >> 4) + ((t) >> 2)) & 7) << 4))
    const int b = m0 >> 13;
    const int kh = ((n0 - 512) >> 8) * 2 + (wn >> 7);   // n-tile is 256 wide
    const int hvb = (wn >> 7) << 6;            // V col base in Vs (0 or 64)
    float* const Vs = (float*)smem;            // [256][128] f32 = 128 KiB
    __syncthreads();                           // all LDS/MFMA reads done
    if (wn & 64) {                             // V-wave: dump acc to LDS
      #pragma unroll
      for (int i = 0; i < 8; i++)
        #pragma unroll
        for (int j2 = 0; j2 < 4; j2++)
          #pragma unroll
          for (int p = 0; p < 4; p++) {
            int t = wm + i * 16 + quad * 4 + p;
            Vs[VSW(t, hvb + j2 * 16 + r)] = acc[i][j2][p];
          }
    }
    __syncthreads();
    if (!(wn & 64)) {                          // K-wave: rope+phi, mul V, reduce
      float kvp[4] = {0.f, 0.f, 0.f, 0.f};
      float ksp[4] = {0.f, 0.f, 0.f, 0.f};
      #pragma unroll
      for (int i = 0; i < 8; i++)
        #pragma unroll
        for (int p = 0; p < 4; p++) {
          int t = wm + i * 16 + quad * 4 + p;
          int pos = (m0 + t) & 8191;
          #pragma unroll
          for (int j2 = 0; j2 < 4; j2++) {
            float v = acc[i][j2][p];
            float vp = __shfl_xor(v, 1, 64);
            int d = j2 * 16 + r;
            float2 cs = rope[pos * 32 + (d >> 1)];
            float rk = (r & 1) ? (vp * cs.y + v * cs.x) : (v * cs.x - vp * cs.y);
            rk = rk > 0.f ? rk + 1.f : __expf(rk);
            kvp[j2] += rk * Vs[VSW(t, hvb + d)];
            ksp[j2] += rk;
          }
        }
      #pragma unroll
      for (int j2 = 0; j2 < 4; j2++) {
        kvp[j2] += __shfl_xor(kvp[j2], 16, 64); kvp[j2] += __shfl_xor(kvp[j2], 32, 64);
        ksp[j2] += __shfl_xor(ksp[j2], 16, 64); ksp[j2] += __shfl_xor(ksp[j2], 32, 64);
      }
      if (lane < 16) {
        int base = (b * 4 + kh) * 64 + r;
        #pragma unroll
        for (int j2 = 0; j2 < 4; j2++) {
          atomicAdd(&KV[base + j2 * 16], kvp[j2]);
          atomicAdd(&Ksum[base + j2 * 16], ksp[j2]);
        }
      }
    }
#undef VSW
  } else {
    // ---- C write (row-major). C/D layout: col = lane&15, row = quad*4 + p
    #pragma unroll
    for (int i = 0; i < 8; i++)
      #pragma unroll
      for (int j2 = 0; j2 < 4; j2++) {
        int row = m0 + wm + i * 16 + quad * 4;
        int col = n0 + wn + j2 * 16 + r;
        #pragma unroll
        for (int p = 0; p < 4; p++) {
          if constexpr (BF16_OUT) {
            ((unsigned short*)Cv)[(size_t)(row + p) * ldc + col] = f2bf(acc[i][j2][p]);
          } else {
            ((float*)Cv)[(size_t)(row + p) * ldc + col] = acc[i][j2][p];
          }
        }
      }
  }
#undef STAGE_A
#undef STAGE_B
#undef LDA8
#undef LDB4
#undef MFMAQ
#undef BAR
#undef VMW
}

// ------- Q path: half-wave (32 lanes) per head, one uint pair per lane -------
__global__ __launch_bounds__(256) void k_qkern(const unsigned short* __restrict__ qkv,
    const float2* __restrict__ rope, const float* __restrict__ KV,
    const float* __restrict__ Ksum, unsigned short* __restrict__ Yb) {
  const int h = threadIdx.x >> 5;   // head 0..7
  const int pr = threadIdx.x & 31;  // rotation pair 0..31
  for (int t = blockIdx.x; t < T_TOK; t += gridDim.x) {
    int b = t >> 13, pos = t & 8191;
    unsigned int qp = *(const unsigned int*)(qkv + (size_t)t * 512 + h * 64 + 2 * pr);
    float qx = bf2f((unsigned short)(qp & 0xffffu));
    float qy = bf2f((unsigned short)(qp >> 16));
    float2 cs = rope[pos * 32 + pr];
    float ar = qx * cs.x - qy * cs.y;
    float ai = qx * cs.y + qy * cs.x;
    ar = ar > 0.f ? ar + 1.f : __expf(ar);
    ai = ai > 0.f ? ai + 1.f : __expf(ai);
    int bk = b * 4 + (h >> 1);
    float2 ks = *(const float2*)(Ksum + bk * 64 + 2 * pr);
    float z = ar * ks.x + ai * ks.y;
    #pragma unroll
    for (int off = 16; off >= 1; off >>= 1) z += __shfl_xor(z, off, 64);  // stays in half-wave
    float2 kv = *(const float2*)(KV + bk * 64 + 2 * pr);
    float inv = 1.0f / (z + 1e-6f);
    unsigned int o = (unsigned int)f2bf(ar * kv.x * inv)
                   | ((unsigned int)f2bf(ai * kv.y * inv) << 16);
    *(unsigned int*)(Yb + (size_t)t * 512 + h * 64 + 2 * pr) = o;
  }
}

extern "C" void kernel_launch(void* const* d_in, const int* in_sizes, int n_in,
                              void* d_out, int out_size, void* d_ws, size_t ws_size,
                              hipStream_t stream) {
  const float* x = (const float*)d_in[0];
  const float* norm_w = (const float*)d_in[1];
  const float* wq = (const float*)d_in[2];
  const float* wk = (const float*)d_in[3];
  const float* wv = (const float*)d_in[4];
  const float* wo = (const float*)d_in[5];
  float* out = (float*)d_out;

  char* ws = (char*)d_ws;
  unsigned short* xn  = (unsigned short*)(ws);                  // 33,554,432 B
  unsigned short* Wb  = (unsigned short*)(ws + 33554432);       //  1,048,576 B
  unsigned short* wob = (unsigned short*)(ws + 34603008);       //    524,288 B
  unsigned short* qkv = (unsigned short*)(ws + 35127296);       // 33,554,432 B (Q only, stride 512)
  float2* rope        = (float2*)(ws + 102236160);              //  2,097,152 B
  float* KV           = (float*)(ws + 104333312);               //      4,096 B
  float* Ksum         = (float*)(ws + 104337408);               //      4,096 B
  unsigned short* Yb  = (unsigned short*)(ws + 104341504);      // 33,554,432 B

  static bool s_attr = false;
  if (!s_attr) {
    (void)hipFuncSetAttribute(reinterpret_cast<const void*>(&k_gemm256<true, true>),
                              hipFuncAttributeMaxDynamicSharedMemorySize, 131072);
    (void)hipFuncSetAttribute(reinterpret_cast<const void*>(&k_gemm256<false, false>),
                              hipFuncAttributeMaxDynamicSharedMemorySize, 131072);
    s_attr = true;
  }

  k_prep<<<10240, 256, 0, stream>>>(x, norm_w, wq, wk, wv, wo, Wb, wob, rope, KV, xn);
  k_gemm256<true, true><<<dim3(128, 4), 512, 131072, stream>>>(
      xn, Wb, (void*)qkv, 512, rope, KV, Ksum);
  k_qkern<<<4096, 256, 0, stream>>>(qkv, rope, KV, Ksum, Yb);
  k_gemm256<false, false><<<dim3(128, 2), 512, 131072, stream>>>(
      Yb, wob, (void*)out, 512, nullptr, nullptr, nullptr);
}

// Round 8
// 207.225 us; speedup vs baseline: 1.1074x; 1.0713x over previous
//
#include <hip/hip_runtime.h>
#include <cmath>

typedef __attribute__((ext_vector_type(8))) short short8;
typedef __attribute__((ext_vector_type(4))) float floatx4;

#define T_TOK 32768
#define DIMK 512

__device__ __forceinline__ unsigned short f2bf(float f) {
  union { float f; unsigned int u; } v; v.f = f;
  unsigned int r = (v.u + 0x7fffu + ((v.u >> 16) & 1u)) >> 16;
  return (unsigned short)r;
}
__device__ __forceinline__ float bf2f(unsigned short h) {
  union { unsigned int u; float f; } v; v.u = ((unsigned int)h) << 16;
  return v.f;
}

// async global->LDS 16B per lane: HW writes lane i at ldsbase + i*16
__device__ __forceinline__ void gload_lds16(const unsigned short* g, unsigned short* ldsbase) {
  __builtin_amdgcn_global_load_lds(
      (const __attribute__((address_space(1))) unsigned int*)g,
      (__attribute__((address_space(3))) unsigned int*)ldsbase, 16, 0, 0);
}

// ------- prep: [blocks 0..2047] weights->bf16 + rope + zero; [2048..4095] rmsnorm -------
// rmsnorm batched 4 tokens/wave (ILP: all 8 float4 loads issued before reductions).
// Wb rows 0..511 = wq; rows 512..1023 interleaved per KV head:
//   row 512+h*128+d <- wk[h*64+d], row 512+h*128+64+d <- wv[h*64+d]
__global__ __launch_bounds__(256) void k_prep(const float* __restrict__ x,
    const float* __restrict__ norm_w, const float* __restrict__ wq,
    const float* __restrict__ wk, const float* __restrict__ wv,
    const float* __restrict__ wo, unsigned short* __restrict__ Wb,
    unsigned short* __restrict__ wob, float2* __restrict__ rope,
    float* __restrict__ KVz, unsigned short* __restrict__ xn) {
  if (blockIdx.x < 2048) {
    int i = blockIdx.x * 256 + threadIdx.x;  // 524288
    float v;
    if (i < 262144) {
      v = wq[i];
    } else {
      int R = i >> 9, col = i & 511;
      int h = (R - 512) >> 7, rem = (R - 512) & 127;
      if (rem < 64) v = wk[(h * 64 + rem) * 512 + col];
      else          v = wv[(h * 64 + rem - 64) * 512 + col];
    }
    Wb[i] = f2bf(v);
    if (i < 262144) {
      wob[i] = f2bf(wo[i]);
      int s = i >> 5, m = i & 31;
      const double c0 = 0.74989420933245582;   // 10^(-1/8)
      double c1 = c0 * c0, c2 = c1 * c1, c3 = c2 * c2, c4 = c3 * c3;
      double p = 1.0;
      if (m & 1)  p *= c0;
      if (m & 2)  p *= c1;
      if (m & 4)  p *= c2;
      if (m & 8)  p *= c3;
      if (m & 16) p *= c4;
      double ang = (double)s * p;
      const double TWO_PI = 6.2831853071795864769;
      double q = rint(ang * (1.0 / TWO_PI));
      double r = fma(-q, TWO_PI, ang);
      float rf = (float)r;
      rope[i] = make_float2(cosf(rf), sinf(rf));
    }
    if (i < 2048) KVz[i] = 0.f;   // zero KV (1024 f32) + Ksum (1024 f32)
  } else {
    // rmsnorm: 2048 blocks x 4 waves x 4 tokens
    int bid = blockIdx.x - 2048;
    int wave = threadIdx.x >> 6, lane = threadIdx.x & 63;
    size_t t0 = ((size_t)bid * 4 + wave) * 4;
    const float4* wr = (const float4*)norm_w;
    float4 w0 = wr[lane * 2], w1 = wr[lane * 2 + 1];
    float4 a[4], b[4];
    #pragma unroll
    for (int j = 0; j < 4; j++) {
      const float4* xr = (const float4*)(x + (t0 + j) * DIMK);
      a[j] = xr[lane * 2];
      b[j] = xr[lane * 2 + 1];
    }
    #pragma unroll
    for (int j = 0; j < 4; j++) {
      float ss = a[j].x * a[j].x + a[j].y * a[j].y + a[j].z * a[j].z + a[j].w * a[j].w
               + b[j].x * b[j].x + b[j].y * b[j].y + b[j].z * b[j].z + b[j].w * b[j].w;
      #pragma unroll
      for (int off = 32; off >= 1; off >>= 1) ss += __shfl_xor(ss, off, 64);
      float scale = rsqrtf(ss * (1.0f / DIMK) + 1e-6f);
      uint4 o;
      o.x = (unsigned int)f2bf(a[j].x * scale * w0.x) | ((unsigned int)f2bf(a[j].y * scale * w0.y) << 16);
      o.y = (unsigned int)f2bf(a[j].z * scale * w0.z) | ((unsigned int)f2bf(a[j].w * scale * w0.w) << 16);
      o.z = (unsigned int)f2bf(b[j].x * scale * w1.x) | ((unsigned int)f2bf(b[j].y * scale * w1.y) << 16);
      o.w = (unsigned int)f2bf(b[j].z * scale * w1.z) | ((unsigned int)f2bf(b[j].w * scale * w1.w) << 16);
      *(uint4*)(xn + (t0 + j) * DIMK + lane * 8) = o;
    }
  }
}

// ------- GEMM: C(M,N) = A(M,512) * Bw(N,512)^T, row-major operands -------
// 256x256 tile, BK=64, 8 waves, 8-phase counted-vmcnt schedule + setprio
// (r2-verified). r2's spread XCD mapping. FUSE (r4-verified + r5 bank rotation):
// n0>=512 tiles hold interleaved K|V columns; epilogue computes rope+phi on K,
// multiplies by V staged in LDS, atomically accumulates KV/Ksum; no C-write.
template <bool BF16_OUT, bool FUSE>
__global__ __launch_bounds__(512, 2) void k_gemm256(const unsigned short* __restrict__ A,
    const unsigned short* __restrict__ Bw, void* __restrict__ Cv, int ldc,
    const float2* __restrict__ rope, float* __restrict__ KV, float* __restrict__ Ksum) {
  constexpr int K = DIMK;
  extern __shared__ __align__(16) unsigned short smem[];
  unsigned short* const AsP = smem;            // [2][16384] shorts (64 KiB)
  unsigned short* const BsP = smem + 32768;    // [2][16384] shorts (64 KiB)

  const int tid = threadIdx.x;
  const int wave = tid >> 6, lane = tid & 63;
  const int r = lane & 15, quad = lane >> 4, r7 = r & 7;
  const int wm = (wave >> 2) * 128, wn = (wave & 3) * 64;

  // r2 spread mapping: XCD chunk of contiguous nid, m fastest within chunk.
  const int nwg = gridDim.x * gridDim.y;
  const int bid = blockIdx.x + gridDim.x * blockIdx.y;
  const int cpx = nwg >> 3;
  const int nid = (bid & 7) * cpx + (bid >> 3);
  const int m0 = (nid & 127) * 256;   // gridDim.x == 128 always here
  const int n0 = (nid >> 7) * 256;

  // staging source (pre-swizzled): lane covers row (lane>>3), col-block (lane&7)^(row&7)
  const int srow = lane >> 3;
  const int scb = (lane & 7) ^ srow;
  const unsigned short* const Asrc = A + (size_t)(m0 + wave * 8 + srow) * K + scb * 8;
  const unsigned short* const Bsrc = Bw + (size_t)(n0 + wave * 8 + srow) * K + scb * 8;
  unsigned short* const Adst = AsP + wave * 8 * 64;  // + buf*16384 + rowoff*64
  unsigned short* const Bdst = BsP + wave * 8 * 64;

#define STAGE_A(buf, h, kt) do { \
    gload_lds16(Asrc + (size_t)((h) * 128) * K + (kt) * 64, Adst + (buf) * 16384 + ((h) * 128) * 64); \
    gload_lds16(Asrc + (size_t)((h) * 128 + 64) * K + (kt) * 64, Adst + (buf) * 16384 + ((h) * 128 + 64) * 64); \
  } while (0)
#define STAGE_B(buf, h, kt) do { \
    gload_lds16(Bsrc + (size_t)((h) * 128) * K + (kt) * 64, Bdst + (buf) * 16384 + ((h) * 128) * 64); \
    gload_lds16(Bsrc + (size_t)((h) * 128 + 64) * K + (kt) * 64, Bdst + (buf) * 16384 + ((h) * 128 + 64) * 64); \
  } while (0)

  short8 af[4][2], b0[2][2], b1[2][2];
  floatx4 acc[8][4];
  #pragma unroll
  for (int i = 0; i < 8; i++)
    #pragma unroll
    for (int jj = 0; jj < 4; jj++)
      acc[i][jj] = (floatx4){0.f, 0.f, 0.f, 0.f};

#define LDA8(buf, ah) do { \
    _Pragma("unroll") for (int ii = 0; ii < 4; ii++) \
      _Pragma("unroll") for (int kk = 0; kk < 2; kk++) \
        af[ii][kk] = *(const short8*)&AsP[(buf) * 16384 + (wm + (ah) * 64 + ii * 16 + r) * 64 + ((kk * 4 + quad) ^ r7) * 8]; \
  } while (0)
#define LDB4(buf, bh, arr) do { \
    _Pragma("unroll") for (int jj = 0; jj < 2; jj++) \
      _Pragma("unroll") for (int kk = 0; kk < 2; kk++) \
        arr[jj][kk] = *(const short8*)&BsP[(buf) * 16384 + (wn + (bh) * 32 + jj * 16 + r) * 64 + ((kk * 4 + quad) ^ r7) * 8]; \
  } while (0)
#define MFMAQ(ah, bh, arr) do { \
    __builtin_amdgcn_s_setprio(1); \
    _Pragma("unroll") for (int ii = 0; ii < 4; ii++) \
      _Pragma("unroll") for (int jj = 0; jj < 2; jj++) \
        _Pragma("unroll") for (int kk = 0; kk < 2; kk++) \
          acc[(ah) * 4 + ii][(bh) * 2 + jj] = __builtin_amdgcn_mfma_f32_16x16x32_bf16( \
              af[ii][kk], arr[jj][kk], acc[(ah) * 4 + ii][(bh) * 2 + jj], 0, 0, 0); \
    __builtin_amdgcn_s_setprio(0); \
  } while (0)
#define BAR() do { asm volatile("" ::: "memory"); __builtin_amdgcn_s_barrier(); asm volatile("" ::: "memory"); } while (0)
#define VMW(n) do { asm volatile("s_waitcnt vmcnt(" #n ")" ::: "memory"); __builtin_amdgcn_sched_barrier(0); } while (0)

  // ---- prologue: kt0 -> buf0 (8 loads), kt1 -> buf1 (8 loads); wait for kt0
  STAGE_A(0, 0, 0); STAGE_B(0, 0, 0); STAGE_A(0, 1, 0); STAGE_B(0, 1, 0);
  STAGE_A(1, 0, 1); STAGE_B(1, 0, 1); STAGE_A(1, 1, 1); STAGE_B(1, 1, 1);
  VMW(8);
  BAR();

  // ---- main: iterations over K-tile pairs (kt, kt+1); kt even->buf0, odd->buf1
  #pragma unroll
  for (int it = 0; it < 3; ++it) {
    const int kt = it * 2;
    // P1: quadrant (Ah0,Bh0) of kt
    LDA8(0, 0); LDB4(0, 0, b0);
    BAR(); MFMAQ(0, 0, b0); BAR();
    // P2: (Ah0,Bh1)
    LDB4(0, 1, b1);
    BAR(); MFMAQ(0, 1, b1); BAR();
    // P3: (Ah1,Bh1); B-buf0 fully read -> stage B-buf0(kt+2)
    LDA8(0, 1); STAGE_B(0, 0, kt + 2); STAGE_B(0, 1, kt + 2);
    BAR(); MFMAQ(1, 1, b1); BAR();
    // P4: (Ah1,Bh0) regs-only; A-buf0 fully read -> stage A-buf0(kt+2)
    STAGE_A(0, 0, kt + 2); STAGE_A(0, 1, kt + 2);
    BAR(); MFMAQ(1, 0, b0); VMW(8); BAR();
    // P5: quadrant (Ah0,Bh0) of kt+1
    LDA8(1, 0); LDB4(1, 0, b0);
    BAR(); MFMAQ(0, 0, b0); BAR();
    // P6
    LDB4(1, 1, b1);
    BAR(); MFMAQ(0, 1, b1); BAR();
    // P7: B-buf1 fully read -> stage B-buf1(kt+3)
    LDA8(1, 1); STAGE_B(1, 0, kt + 3); STAGE_B(1, 1, kt + 3);
    BAR(); MFMAQ(1, 1, b1); BAR();
    // P8: A-buf1 fully read -> stage A-buf1(kt+3)
    STAGE_A(1, 0, kt + 3); STAGE_A(1, 1, kt + 3);
    BAR(); MFMAQ(1, 0, b0); VMW(8); BAR();
  }

  // ---- epilogue: kt=6 (buf0), kt=7 (buf1); nothing left to stage
  LDA8(0, 0); LDB4(0, 0, b0);
  BAR(); MFMAQ(0, 0, b0); BAR();
  LDB4(0, 1, b1);
  BAR(); MFMAQ(0, 1, b1); BAR();
  LDA8(0, 1);
  BAR(); MFMAQ(1, 1, b1); BAR();
  MFMAQ(1, 0, b0); VMW(0); BAR();
  LDA8(1, 0); LDB4(1, 0, b0);
  BAR(); MFMAQ(0, 0, b0); BAR();
  LDB4(1, 1, b1);
  BAR(); MFMAQ(0, 1, b1); BAR();
  LDA8(1, 1);
  BAR(); MFMAQ(1, 1, b1); BAR();
  MFMAQ(1, 0, b0);

  if (FUSE && n0 >= 512) {
    // ---- fused KV/Ksum epilogue (r4-verified; r5's bank rotation).
    // acc cols (wn groups): 0=K_h, 64=V_h, 128=K_{h+1}, 192=V_{h+1}.
#define VSW(t, d) ((t) * 128 + ((d) & 15) + (((((d) >> 4) + ((t) >> 2)) & 7) << 4))
    const int b = m0 >> 13;
    const int kh = ((n0 - 512) >> 8) * 2 + (wn >> 7);   // n-tile is 256 wide
    const int hvb = (wn >> 7) << 6;            // V col base in Vs (0 or 64)
    float* const Vs = (float*)smem;            // [256][128] f32 = 128 KiB
    __syncthreads();                           // all LDS/MFMA reads done
    if (wn & 64) {                             // V-wave: dump acc to LDS
      #pragma unroll
      for (int i = 0; i < 8; i++)
        #pragma unroll
        for (int j2 = 0; j2 < 4; j2++)
          #pragma unroll
          for (int p = 0; p < 4; p++) {
            int t = wm + i * 16 + quad * 4 + p;
            Vs[VSW(t, hvb + j2 * 16 + r)] = acc[i][j2][p];
          }
    }
    __syncthreads();
    if (!(wn & 64)) {                          // K-wave: rope+phi, mul V, reduce
      float kvp[4] = {0.f, 0.f, 0.f, 0.f};
      float ksp[4] = {0.f, 0.f, 0.f, 0.f};
      #pragma unroll
      for (int i = 0; i < 8; i++)
        #pragma unroll
        for (int p = 0; p < 4; p++) {
          int t = wm + i * 16 + quad * 4 + p;
          int pos = (m0 + t) & 8191;
          #pragma unroll
          for (int j2 = 0; j2 < 4; j2++) {
            float v = acc[i][j2][p];
            float vp = __shfl_xor(v, 1, 64);
            int d = j2 * 16 + r;
            float2 cs = rope[pos * 32 + (d >> 1)];
            float rk = (r & 1) ? (vp * cs.y + v * cs.x) : (v * cs.x - vp * cs.y);
            rk = rk > 0.f ? rk + 1.f : __expf(rk);
            kvp[j2] += rk * Vs[VSW(t, hvb + d)];
            ksp[j2] += rk;
          }
        }
      #pragma unroll
      for (int j2 = 0; j2 < 4; j2++) {
        kvp[j2] += __shfl_xor(kvp[j2], 16, 64); kvp[j2] += __shfl_xor(kvp[j2], 32, 64);
        ksp[j2] += __shfl_xor(ksp[j2], 16, 64); ksp[j2] += __shfl_xor(ksp[j2], 32, 64);
      }
      if (lane < 16) {
        int base = (b * 4 + kh) * 64 + r;
        #pragma unroll
        for (int j2 = 0; j2 < 4; j2++) {
          atomicAdd(&KV[base + j2 * 16], kvp[j2]);
          atomicAdd(&Ksum[base + j2 * 16], ksp[j2]);
        }
      }
    }
#undef VSW
  } else {
    // ---- C write (row-major). C/D layout: col = lane&15, row = quad*4 + p
    #pragma unroll
    for (int i = 0; i < 8; i++)
      #pragma unroll
      for (int j2 = 0; j2 < 4; j2++) {
        int row = m0 + wm + i * 16 + quad * 4;
        int col = n0 + wn + j2 * 16 + r;
        #pragma unroll
        for (int p = 0; p < 4; p++) {
          if constexpr (BF16_OUT) {
            ((unsigned short*)Cv)[(size_t)(row + p) * ldc + col] = f2bf(acc[i][j2][p]);
          } else {
            ((float*)Cv)[(size_t)(row + p) * ldc + col] = acc[i][j2][p];
          }
        }
      }
  }
#undef STAGE_A
#undef STAGE_B
#undef LDA8
#undef LDB4
#undef MFMAQ
#undef BAR
#undef VMW
}

// ------- Q path: 8 tokens per block, batched loads for MLP -------
// half-wave (32 lanes) per head; KV/Ksum loaded once (b,h fixed per block).
__global__ __launch_bounds__(256) void k_qkern(const unsigned short* __restrict__ qkv,
    const float2* __restrict__ rope, const float* __restrict__ KV,
    const float* __restrict__ Ksum, unsigned short* __restrict__ Yb) {
  const int h = threadIdx.x >> 5;   // head 0..7
  const int pr = threadIdx.x & 31;  // rotation pair 0..31
  const int t0 = blockIdx.x * 8;    // 4096 blocks x 8 tokens
  const int b = t0 >> 13;           // same batch for all 8 (8 | 8192)
  const int bk = b * 4 + (h >> 1);
  const float2 ks = *(const float2*)(Ksum + bk * 64 + 2 * pr);
  const float2 kv = *(const float2*)(KV + bk * 64 + 2 * pr);
  unsigned int qp[8]; float2 cs[8];
  #pragma unroll
  for (int j = 0; j < 8; j++) {
    int t = t0 + j;
    qp[j] = *(const unsigned int*)(qkv + (size_t)t * 512 + h * 64 + 2 * pr);
    cs[j] = rope[(t & 8191) * 32 + pr];
  }
  float ar[8], ai[8], z[8];
  #pragma unroll
  for (int j = 0; j < 8; j++) {
    float qx = bf2f((unsigned short)(qp[j] & 0xffffu));
    float qy = bf2f((unsigned short)(qp[j] >> 16));
    float a = qx * cs[j].x - qy * cs[j].y;
    float i2 = qx * cs[j].y + qy * cs[j].x;
    a  = a  > 0.f ? a  + 1.f : __expf(a);
    i2 = i2 > 0.f ? i2 + 1.f : __expf(i2);
    ar[j] = a; ai[j] = i2;
    z[j] = a * ks.x + i2 * ks.y;
  }
  #pragma unroll
  for (int off = 16; off >= 1; off >>= 1)
    #pragma unroll
    for (int j = 0; j < 8; j++)
      z[j] += __shfl_xor(z[j], off, 64);  // stays in half-wave
  #pragma unroll
  for (int j = 0; j < 8; j++) {
    float inv = 1.0f / (z[j] + 1e-6f);
    unsigned int o = (unsigned int)f2bf(ar[j] * kv.x * inv)
                   | ((unsigned int)f2bf(ai[j] * kv.y * inv) << 16);
    *(unsigned int*)(Yb + (size_t)(t0 + j) * 512 + h * 64 + 2 * pr) = o;
  }
}

extern "C" void kernel_launch(void* const* d_in, const int* in_sizes, int n_in,
                              void* d_out, int out_size, void* d_ws, size_t ws_size,
                              hipStream_t stream) {
  const float* x = (const float*)d_in[0];
  const float* norm_w = (const float*)d_in[1];
  const float* wq = (const float*)d_in[2];
  const float* wk = (const float*)d_in[3];
  const float* wv = (const float*)d_in[4];
  const float* wo = (const float*)d_in[5];
  float* out = (float*)d_out;

  char* ws = (char*)d_ws;
  unsigned short* xn  = (unsigned short*)(ws);                  // 33,554,432 B
  unsigned short* Wb  = (unsigned short*)(ws + 33554432);       //  1,048,576 B
  unsigned short* wob = (unsigned short*)(ws + 34603008);       //    524,288 B
  unsigned short* qkv = (unsigned short*)(ws + 35127296);       // 33,554,432 B (Q only, stride 512)
  float2* rope        = (float2*)(ws + 102236160);              //  2,097,152 B
  float* KV           = (float*)(ws + 104333312);               //      4,096 B
  float* Ksum         = (float*)(ws + 104337408);               //      4,096 B
  unsigned short* Yb  = (unsigned short*)(ws);                  // aliases xn (dead after GEMM1)

  static bool s_attr = false;
  if (!s_attr) {
    (void)hipFuncSetAttribute(reinterpret_cast<const void*>(&k_gemm256<true, true>),
                              hipFuncAttributeMaxDynamicSharedMemorySize, 131072);
    (void)hipFuncSetAttribute(reinterpret_cast<const void*>(&k_gemm256<false, false>),
                              hipFuncAttributeMaxDynamicSharedMemorySize, 131072);
    s_attr = true;
  }

  k_prep<<<4096, 256, 0, stream>>>(x, norm_w, wq, wk, wv, wo, Wb, wob, rope, KV, xn);
  k_gemm256<true, true><<<dim3(128, 4), 512, 131072, stream>>>(
      xn, Wb, (void*)qkv, 512, rope, KV, Ksum);
  k_qkern<<<4096, 256, 0, stream>>>(qkv, rope, KV, Ksum, Yb);
  k_gemm256<false, false><<<dim3(128, 2), 512, 131072, stream>>>(
      Yb, wob, (void*)out, 512, nullptr, nullptr, nullptr);
}